// Round 8
// baseline (527.323 us; speedup 1.0000x reference)
//
#include <hip/hip_runtime.h>
#include <cstdint>
#include <cstddef>

// ---------- types ----------
typedef __attribute__((ext_vector_type(8))) __bf16 bf16x8;   // MFMA A/B frag (4 VGPRs)
typedef __attribute__((ext_vector_type(4))) float f32x4;     // MFMA C/D frag
typedef __attribute__((ext_vector_type(4))) unsigned short u16x4;
typedef unsigned short u16;

// Problem constants
#define BATCH 4
#define SEQ 2048
#define DIM 2048
#define NH 16
#define HD 128
#define BH (BATCH*NH)          // 64
#define MROWS (BATCH*SEQ)      // 8192

__device__ static inline u16 f2bf(float f) {
  union { float f; uint32_t u; } v; v.f = f;
  uint32_t r = v.u + 0x7fffu + ((v.u >> 16) & 1u);
  return (u16)(r >> 16);
}

// pack two fp32 -> two bf16 (round-half-up) in one v_perm
__device__ static inline uint32_t pkbf(float lo, float hi) {
  union { float f; uint32_t u; } a, b;
  a.f = lo; b.f = hi;
  return __builtin_amdgcn_perm(b.u + 0x8000u, a.u + 0x8000u, 0x07060302u);
}

// pack two fp32 -> two bf16 (RNE) in ONE VALU op
__device__ static inline uint32_t cvtpk(float lo, float hi) {
  uint32_t r;
  asm("v_cvt_pk_bf16_f32 %0, %1, %2" : "=v"(r) : "v"(lo), "v"(hi));
  return r;
}

__device__ static inline void gload_lds16(const void* g, void* l) {
  __builtin_amdgcn_global_load_lds(
      (const __attribute__((address_space(1))) unsigned int*)g,
      (__attribute__((address_space(3))) unsigned int*)l, 16, 0, 0);
}

__device__ static inline f32x4 mfma_bf16(bf16x8 a, bf16x8 b, f32x4 c) {
  return __builtin_amdgcn_mfma_f32_16x16x32_bf16(a, b, c, 0, 0, 0);
}

// ---------- fused prologue: all fp32->bf16 converts + bias scale, ONE dispatch ----------
#define NB_X   (MROWS * DIM / 1024)       // 16384 blocks
#define NB_WQ  (3 * DIM * DIM / 1024)     // 12288 blocks
#define NB_WO  (DIM * DIM / 1024)         // 4096 blocks
#define NB_BIAS (3 * DIM / 256)           // 24 blocks
__global__ __launch_bounds__(256) void fused_cvt_kernel(
    const float4* __restrict__ x, u16x4* __restrict__ xb,
    const float4* __restrict__ wq, u16x4* __restrict__ wqb,
    const float4* __restrict__ wo, u16x4* __restrict__ wob,
    const float* __restrict__ bq, float* __restrict__ bqs, float scale2) {
  const int b = blockIdx.x;
  const int t = threadIdx.x;
  if (b < NB_X) {
    int i = b * 256 + t;
    float4 f = x[i];
    u16x4 o = { f2bf(f.x), f2bf(f.y), f2bf(f.z), f2bf(f.w) };
    xb[i] = o;
  } else if (b < NB_X + NB_WQ) {
    int i = (b - NB_X) * 256 + t;
    float4 f = wq[i];
    float s = (i < DIM * DIM / 4) ? scale2 : 1.0f;
    u16x4 o = { f2bf(f.x * s), f2bf(f.y * s), f2bf(f.z * s), f2bf(f.w * s) };
    wqb[i] = o;
  } else if (b < NB_X + NB_WQ + NB_WO) {
    int i = (b - NB_X - NB_WQ) * 256 + t;
    float4 f = wo[i];
    u16x4 o = { f2bf(f.x), f2bf(f.y), f2bf(f.z), f2bf(f.w) };
    wob[i] = o;
  } else {
    int i = (b - NB_X - NB_WQ - NB_WO) * 256 + t;
    bqs[i] = bq[i] * ((i < DIM) ? scale2 : 1.0f);
  }
}

// ---------- GEMM fragment helpers (256x256 8-phase) ----------
__device__ __forceinline__ void ld_a(const char* sA, int wm, int ln, int quad,
                                     bf16x8 (&af)[4][2]) {
#pragma unroll
  for (int i = 0; i < 4; i++) {
    int r = wm * 64 + i * 16 + ln;
#pragma unroll
    for (int ks = 0; ks < 2; ks++) {
      int c = (ks * 4 + quad) ^ (r & 7);
      af[i][ks] = *(const bf16x8*)(sA + r * 128 + c * 16);
    }
  }
}

__device__ __forceinline__ void ld_b(const char* sB, int wn, int ln, int quad,
                                     bf16x8 (&bf)[2][2]) {
#pragma unroll
  for (int j = 0; j < 2; j++) {
    int r = wn * 32 + j * 16 + ln;
#pragma unroll
    for (int ks = 0; ks < 2; ks++) {
      int c = (ks * 4 + quad) ^ (r & 7);
      bf[j][ks] = *(const bf16x8*)(sB + r * 128 + c * 16);
    }
  }
}

template<int QM, int QN>
__device__ __forceinline__ void mm16(f32x4 (&acc)[8][4], const bf16x8 (&af)[4][2],
                                     const bf16x8 (&bf)[2][2]) {
  __builtin_amdgcn_s_setprio(1);
#pragma unroll
  for (int i = 0; i < 4; i++)
#pragma unroll
    for (int j = 0; j < 2; j++)
#pragma unroll
      for (int ks = 0; ks < 2; ks++)
        acc[QM * 4 + i][QN * 2 + j] =
            mfma_bf16(af[i][ks], bf[j][ks], acc[QM * 4 + i][QN * 2 + j]);
  __builtin_amdgcn_s_setprio(0);
}

// ---------- GEMM: C[M,N] = A[M,K] * W[N,K]^T + bias ----------
// 256x256 tile, BK=64, 8 waves (2M x 4N), 8-phase schedule, SINGLE barrier
// per phase (R7, measured 178us / MfmaUtil 52%; LDS-BW ceiling ~62%).
// XCD swizzle, bx-OUTER / by-INNER (gy == 32 both launches).
template<int EPI>
__global__ __launch_bounds__(512, 2) void gemm_bt_kernel(
    const u16* __restrict__ A, const u16* __restrict__ W,
    const float* __restrict__ bias, float* __restrict__ Cout,
    int M, int N, int K,
    u16* __restrict__ qb, u16* __restrict__ kb, u16* __restrict__ vtb) {
  __shared__ __align__(16) char lds[131072];

  const int tid = threadIdx.x;
  const int wave = tid >> 6, lane = tid & 63;
  const int quad = lane >> 4, ln = lane & 15;
  const int wm = wave >> 2;             // 0..1
  const int wn = wave & 3;              // 0..3

  // XCD-aware swizzle (nwg % 8 == 0; gy = M/256 = 32 -> 4 rows/XCD)
  const int bid = blockIdx.x;
  const int c = bid & 7;                // XCD id
  const int u = bid >> 3;               // within-XCD index
  const int bx = u >> 2;                // bx-outer
  const int by = c * 4 + (u & 3);       // by-inner, contiguous per XCD
  const int mbase = by * 256;
  const int nbase = bx * 256;

  f32x4 acc[8][4];
#pragma unroll
  for (int i = 0; i < 8; i++)
#pragma unroll
    for (int j = 0; j < 4; j++) acc[i][j] = (f32x4){0.f, 0.f, 0.f, 0.f};

  // loop-invariant staging geometry: one granule = 1024 chunks x 16B = 16KB,
  // chunk = wave*128 + issue*64 + lane (linear LDS dest for global_load_lds).
  const u16* gA[2][2];  // [granule][issue]
  const u16* gB[2][2];
  int stOff0, stOff1;
  {
    stOff0 = (wave * 128 + lane) * 16;
    stOff1 = stOff0 + 1024;
#pragma unroll
    for (int s = 0; s < 2; s++) {
      int chunk = wave * 128 + s * 64 + lane;
      int r = chunk >> 3, sc = chunk & 7;
      int gc = sc ^ (r & 7);             // pre-swizzled global 16B chunk
#pragma unroll
      for (int g = 0; g < 2; g++) {
        int ra = (r >> 6) * 128 + g * 64 + (r & 63);
        gA[g][s] = A + (size_t)(mbase + ra) * K + gc * 8;
        int rb = (r >> 5) * 64 + g * 32 + (r & 31);
        gB[g][s] = W + (size_t)(nbase + rb) * K + gc * 8;
      }
    }
  }

  const int NT = K >> 6;                 // 32 k-tiles (power of 2)
  const int NITER = NT >> 1;             // 16 iterations x 2 k-tiles

#define SLOT_A(d, g) (lds + (((d) * 2 + (g)) << 14))
#define SLOT_B(d, g) (lds + 65536 + (((d) * 2 + (g)) << 14))
#define STAGE_A(d, t, g) do { char* sb_ = SLOT_A(d, g); \
    size_t ko_ = (size_t)((t) & (NT - 1)) * 64; \
    gload_lds16(gA[g][0] + ko_, sb_ + stOff0); \
    gload_lds16(gA[g][1] + ko_, sb_ + stOff1); } while (0)
#define STAGE_B(d, t, g) do { char* sb_ = SLOT_B(d, g); \
    size_t ko_ = (size_t)((t) & (NT - 1)) * 64; \
    gload_lds16(gB[g][0] + ko_, sb_ + stOff0); \
    gload_lds16(gB[g][1] + ko_, sb_ + stOff1); } while (0)
#define BAR  asm volatile("s_barrier" ::: "memory")
#define BARV asm volatile("s_waitcnt vmcnt(6)\n\ts_barrier" ::: "memory")

  // prologue: k-tile 0 fully + k-tile 1 first 3 granules (14 loads);
  // vmcnt(6) drains the oldest 8 = all of k-tile 0.
  STAGE_A(0, 0, 0); STAGE_B(0, 0, 0); STAGE_A(0, 0, 1); STAGE_B(0, 0, 1);
  STAGE_A(1, 1, 0); STAGE_B(1, 1, 0); STAGE_A(1, 1, 1);
  BARV;

  for (int it = 0; it < NITER; ++it) {
    const int t = it << 1;               // even: k-tile t in d=0, t+1 in d=1
    bf16x8 af[4][2], bq0[2][2], bq1[2][2];
    // ---- phase 1: quadrant (0,0) of tile t ----
    ld_a(SLOT_A(0, 0), wm, ln, quad, af);
    ld_b(SLOT_B(0, 0), wn, ln, quad, bq0);
    STAGE_B(1, t + 1, 1);                // last granule of t+1
    mm16<0, 0>(acc, af, bq0); BAR;
    // ---- phase 2: quadrant (0,1) ----
    ld_b(SLOT_B(0, 1), wn, ln, quad, bq1);
    STAGE_A(0, t + 2, 0);                // A-g0(t) consumed in ph1
    mm16<0, 1>(acc, af, bq1); BAR;
    // ---- phase 3: quadrant (1,0) ----
    ld_a(SLOT_A(0, 1), wm, ln, quad, af);
    STAGE_B(0, t + 2, 0);                // B-g0(t) consumed in ph1
    mm16<1, 0>(acc, af, bq0); BAR;
    // ---- phase 4: quadrant (1,1) ----
    STAGE_A(0, t + 2, 1);                // A-g1(t) consumed in ph3
    mm16<1, 1>(acc, af, bq1); BARV;
    // ---- phase 5: quadrant (0,0) of tile t+1 ----
    ld_a(SLOT_A(1, 0), wm, ln, quad, af);
    ld_b(SLOT_B(1, 0), wn, ln, quad, bq0);
    STAGE_B(0, t + 2, 1);                // B-g1(t) consumed in ph2
    mm16<0, 0>(acc, af, bq0); BAR;
    // ---- phase 6: quadrant (0,1) ----
    ld_b(SLOT_B(1, 1), wn, ln, quad, bq1);
    STAGE_A(1, t + 3, 0);                // A-g0(t+1) consumed in ph5
    mm16<0, 1>(acc, af, bq1); BAR;
    // ---- phase 7: quadrant (1,0) ----
    ld_a(SLOT_A(1, 1), wm, ln, quad, af);
    STAGE_B(1, t + 3, 0);                // B-g0(t+1) consumed in ph5
    mm16<1, 0>(acc, af, bq0); BAR;
    // ---- phase 8: quadrant (1,1) ----
    STAGE_A(1, t + 3, 1);                // A-g1(t+1) consumed in ph7
    mm16<1, 1>(acc, af, bq1); BARV;
  }
#undef SLOT_A
#undef SLOT_B
#undef STAGE_A
#undef STAGE_B
#undef BAR
#undef BARV

  // epilogue. C/D layout: col = lane&15, row = quad*4 + reg.
  // row = mbase + wm*128 + i*16 + quad*4 + r ; col = nbase + wn*64 + j*16 + ln
  if (EPI == 0 || (nbase >> 11) < 2) {
#pragma unroll
    for (int i = 0; i < 8; i++) {
#pragma unroll
      for (int j = 0; j < 4; j++) {
        int col = nbase + wn * 64 + j * 16 + ln;
        float bv = bias[col];
#pragma unroll
        for (int r = 0; r < 4; r++) {
          int row = mbase + wm * 128 + i * 16 + quad * 4 + r;
          float val = acc[i][j][r] + bv;
          if (EPI == 0) {
            Cout[(size_t)row * N + col] = val;
          } else {
            int b = row >> 11, s = row & 2047;
            int m3 = col >> 11, h = (col >> 7) & 15, d = col & 127;
            int bh = b * NH + h;
            u16 bfv = f2bf(val);
            if (m3 == 0) qb[((size_t)bh * SEQ + s) * HD + d] = bfv;
            else         kb[((size_t)bh * SEQ + s) * HD + d] = bfv;
          }
        }
      }
    }
  } else {
    // V block: transpose via LDS. Full tile = 256 cols(d) x 256 rows(s) bf16
    // = 128KB (exactly fits). Row = 512B = 32 x 16B chunks, chunk index
    // XOR-swizzled with (col&31). Wrap-staged gloads still target LDS:
    // drain ALL waves' vmem-LDS writes before reuse (vmcnt per-wave -> +barrier).
    asm volatile("s_waitcnt vmcnt(0)" ::: "memory");
    __syncthreads();
#pragma unroll
    for (int i = 0; i < 8; i++) {
      int rl0 = wm * 128 + i * 16 + quad * 4;   // 4 consecutive s-rows
      int cs = rl0 >> 3;                         // 16B chunk in s-dim (0..31)
      int half = (quad & 1);                     // 8B half of the chunk
#pragma unroll
      for (int j = 0; j < 4; j++) {
        int cl = wn * 64 + j * 16 + ln;          // col_local = d-dim 0..255
        float bv = bias[nbase + cl];
        uint2 w2;
        w2.x = pkbf(acc[i][j][0] + bv, acc[i][j][1] + bv);
        w2.y = pkbf(acc[i][j][2] + bv, acc[i][j][3] + bv);
        int cc = cs ^ (cl & 31);
        *(uint2*)(lds + cl * 512 + cc * 16 + half * 8) = w2;
      }
    }
    __syncthreads();
    // vtb[bh][d][s]: heads contiguous -> linear in cl since nbase%256==0
    u16* vdst = vtb + ((size_t)((mbase >> 11) * 2048 + (nbase & 2047))) * SEQ
                + (mbase & 2047);
#pragma unroll
    for (int rd = 0; rd < 16; rd++) {
      int idx = rd * 512 + tid;                  // 0..8191
      int cl = idx >> 5, cs = idx & 31;
      f32x4 v = *(const f32x4*)(lds + cl * 512 + ((cs ^ (cl & 31)) * 16));
      *(f32x4*)(vdst + (size_t)cl * SEQ + cs * 8) = v;
    }
  }
}

// ---------- flash attention: one-tile software pipeline ----------
// KVB=64, 80KB LDS, 2 blocks/CU, XCD swizzle. NEW (R8): PV(t-1) runs
// concurrently with SM(t) so the softmax VALU hides under PV's MFMA.
// Staging split: K(t+1) at top of iter (prefetch dist = 1 iter), V(t+1)
// after the end-of-iter barrier (V(t-1)'s buffer only free after PV(t-1)).
// vmcnt induction (per-wave instr counts, 4 per stage):
//   steady state at the wait: [V(t-1),K(t),V(t),K(t+1)] = 16 in flight;
//   vmcnt(8) drains exactly [V(t-1),K(t)] = what QK(t)+PV(t-1) need.
//   Prologue must stage all K0 THEN all V0 (drain order).
//   Tail: vmcnt(8) drains V(NT-1); PV(NT-1) after barrier.
// P(t-1) is consumed via pb register fragments hoisted BEFORE SM(t)
// overwrites the (single-buffered, per-wave) P region.
__global__ __launch_bounds__(256, 2) void attn_kernel(
    const u16* __restrict__ Q, const u16* __restrict__ Km,
    const u16* __restrict__ Vt, u16* __restrict__ Out) {
  __shared__ __align__(16) char lds[81920];
  // buf0: K[0..16K) V[16K..32K); buf1: K[32K..48K) V[48K..64K); P at 64K.
  char* ldsP = lds + 65536;          // per wave 4KB: [32 q][128B] swizzled (&7)

  const int tid = threadIdx.x;
  const int wave = tid >> 6, lane = tid & 63;
  const int quad = lane >> 4, ln = lane & 15;

  // XCD swizzle: XCD c (wg%8==c) gets bh in [8c, 8c+8), q-tile fastest.
  const int wg = blockIdx.x;
  const int swz = (wg & 7) * 128 + (wg >> 3);
  const int bh = swz >> 4;
  const int q0 = (swz & 15) * 128;

  const u16* Qb = Q + (size_t)bh * SEQ * HD;
  const u16* Kb = Km + (size_t)bh * SEQ * HD;
  const u16* Vb = Vt + (size_t)bh * HD * SEQ;

  // Q fragments (bytes serve as MFMA B-operand: B[k=quad*8+j][n=ln])
  bf16x8 qf[2][4];
#pragma unroll
  for (int nt = 0; nt < 2; nt++)
#pragma unroll
    for (int ks = 0; ks < 4; ks++) {
      int row = q0 + wave * 32 + nt * 16 + ln;
      qf[nt][ks] = *(const bf16x8*)(Qb + (size_t)row * HD + ks * 32 + quad * 8);
    }

  // O^T accumulators: [8 d-tiles][2 q-tiles], C-layout row=d, col=q=ln
  f32x4 oacc[8][2];
#pragma unroll
  for (int mt = 0; mt < 8; mt++)
#pragma unroll
    for (int nt = 0; nt < 2; nt++) oacc[mt][nt] = (f32x4){0.f, 0.f, 0.f, 0.f};
  float l_s[2] = {0.f, 0.f};

  char* Pw = ldsP + wave * 4096;

  // per-lane staging geometry (loop-invariant)
  const int chunk0 = wave * 256 + lane;
  const u16* gKp[4]; const u16* gVp[4]; int ldsOff[4];
#pragma unroll
  for (int s4 = 0; s4 < 4; s4++) {
    int chunk = chunk0 + s4 * 64;              // 0..1023
    int rk = chunk >> 4, ck = chunk & 15;
    int gk = ck ^ (rk & 15);
    gKp[s4] = Kb + (size_t)rk * HD + gk * 8;
    int rv = chunk >> 3, cv = chunk & 7;
    int gv = cv ^ (rv & 7);
    gVp[s4] = Vb + (size_t)rv * SEQ + gv * 8;
    ldsOff[s4] = chunk * 16;
  }

  // prologue: stage K(0) first, THEN V(0) (drain-order matters for vmcnt(8))
#pragma unroll
  for (int s4 = 0; s4 < 4; s4++) gload_lds16(gKp[s4], lds + ldsOff[s4]);
#pragma unroll
  for (int s4 = 0; s4 < 4; s4++) gload_lds16(gVp[s4], lds + 16384 + ldsOff[s4]);

  const int NTT = SEQ / 64;                    // 32
  for (int kt = 0; kt < NTT; kt++) {
    // stage K(kt+1) -> Kbuf[(kt+1)&1] (overwrites K(kt-1), reads done @ last BAR)
    {
      int t = (kt + 1) & (NTT - 1);
      char* buf = lds + ((kt + 1) & 1) * 32768;
#pragma unroll
      for (int s4 = 0; s4 < 4; s4++)
        gload_lds16(gKp[s4] + (size_t)t * 64 * HD, buf + ldsOff[s4]);
    }
    // drain [V(kt-1), K(kt)] (8 oldest of 16); all waves -> barrier
    asm volatile("s_waitcnt vmcnt(8)\n\ts_barrier" ::: "memory");

    const char* ldsK = lds + (kt & 1) * 32768;

    // ---- QK^T(kt): S^T = K·Q^T (log2-domain scores) ----
    f32x4 st[4][2];
#pragma unroll
    for (int mt = 0; mt < 4; mt++)
#pragma unroll
      for (int nt = 0; nt < 2; nt++) st[mt][nt] = (f32x4){0.f, 0.f, 0.f, 0.f};
    __builtin_amdgcn_s_setprio(1);
#pragma unroll
    for (int ks = 0; ks < 4; ks++) {
      bf16x8 kf[4];
#pragma unroll
      for (int mt = 0; mt < 4; mt++) {
        int row = mt * 16 + ln;
        int ch = (ks * 4 + quad) ^ (row & 15);
        kf[mt] = *(const bf16x8*)(ldsK + row * 256 + ch * 16);
      }
#pragma unroll
      for (int mt = 0; mt < 4; mt++)
#pragma unroll
        for (int nt = 0; nt < 2; nt++)
          st[mt][nt] = mfma_bf16(kf[mt], qf[nt][ks], st[mt][nt]);
    }
    __builtin_amdgcn_s_setprio(0);

    // ---- hoist P(kt-1) fragments to registers BEFORE SM overwrites P ----
    bf16x8 pb[2][2];
    if (kt > 0) {
#pragma unroll
      for (int ks2 = 0; ks2 < 2; ks2++)
#pragma unroll
        for (int nt = 0; nt < 2; nt++) {
          int cc = (ks2 * 4 + quad) ^ (ln & 7);
          pb[ks2][nt] = *(const bf16x8*)(Pw + (nt * 16 + ln) * 128 + cc * 16);
        }
    }

    // ---- SM(kt): p = exp2(s), P(kt) -> LDS  (VALU; overlaps PV below) ----
#pragma unroll
    for (int nt = 0; nt < 2; nt++) {
      float lp = 0.f;
      u16* prow = (u16*)(Pw + (nt * 16 + ln) * 128);
#pragma unroll
      for (int mt = 0; mt < 4; mt++) {
        float p0 = __builtin_amdgcn_exp2f(st[mt][nt][0]);
        float p1 = __builtin_amdgcn_exp2f(st[mt][nt][1]);
        float p2 = __builtin_amdgcn_exp2f(st[mt][nt][2]);
        float p3 = __builtin_amdgcn_exp2f(st[mt][nt][3]);
        lp += (p0 + p1) + (p2 + p3);
        uint2 w2;
        w2.x = cvtpk(p0, p1);
        w2.y = cvtpk(p2, p3);
        int cc = (mt * 2 + (quad >> 1)) ^ (ln & 7);
        *(uint2*)((char*)prow + cc * 16 + (quad & 1) * 8) = w2;
      }
      l_s[nt] += lp;
    }

    // ---- PV(kt-1): O^T += V^T·P^T — independent of SM(kt), MFMA pipe ----
    if (kt > 0) {
      const char* ldsVp = lds + (((kt - 1) & 1) * 32768) + 16384;
      __builtin_amdgcn_s_setprio(1);
#pragma unroll
      for (int ks2 = 0; ks2 < 2; ks2++) {
        bf16x8 vf[8];
#pragma unroll
        for (int mt = 0; mt < 8; mt++) {
          int row = mt * 16 + ln;
          int ch = (ks2 * 4 + quad) ^ (row & 7);
          vf[mt] = *(const bf16x8*)(ldsVp + row * 128 + ch * 16);
        }
#pragma unroll
        for (int mt = 0; mt < 8; mt++)
#pragma unroll
          for (int nt = 0; nt < 2; nt++)
            oacc[mt][nt] = mfma_bf16(vf[mt], pb[ks2][nt], oacc[mt][nt]);
      }
      __builtin_amdgcn_s_setprio(0);
    }

    // all waves: PV(kt-1) V-reads + QK(kt) K-reads done -> safe to overwrite
    asm volatile("s_waitcnt lgkmcnt(0)\n\ts_barrier" ::: "memory");

    // stage V(kt+1) -> Vbuf[(kt+1)&1] (overwrites V(kt-1), freed just above)
    {
      int t = (kt + 1) & (NTT - 1);
      char* buf = lds + ((kt + 1) & 1) * 32768;
#pragma unroll
      for (int s4 = 0; s4 < 4; s4++)
        gload_lds16(gVp[s4] + t * 64, buf + 16384 + ldsOff[s4]);
    }
  }

  // ---- tail: PV(NT-1). vmcnt(8) drains V(NT-1) (oldest 4 of 12). ----
  asm volatile("s_waitcnt vmcnt(8)\n\ts_barrier" ::: "memory");
  {
    bf16x8 pb[2][2];
#pragma unroll
    for (int ks2 = 0; ks2 < 2; ks2++)
#pragma unroll
      for (int nt = 0; nt < 2; nt++) {
        int cc = (ks2 * 4 + quad) ^ (ln & 7);
        pb[ks2][nt] = *(const bf16x8*)(Pw + (nt * 16 + ln) * 128 + cc * 16);
      }
    const char* ldsVp = lds + (((NTT - 1) & 1) * 32768) + 16384;
    __builtin_amdgcn_s_setprio(1);
#pragma unroll
    for (int ks2 = 0; ks2 < 2; ks2++) {
      bf16x8 vf[8];
#pragma unroll
      for (int mt = 0; mt < 8; mt++) {
        int row = mt * 16 + ln;
        int ch = (ks2 * 4 + quad) ^ (row & 7);
        vf[mt] = *(const bf16x8*)(ldsVp + row * 128 + ch * 16);
      }
#pragma unroll
      for (int mt = 0; mt < 8; mt++)
#pragma unroll
        for (int nt = 0; nt < 2; nt++)
          oacc[mt][nt] = mfma_bf16(vf[mt], pb[ks2][nt], oacc[mt][nt]);
    }
    __builtin_amdgcn_s_setprio(0);
  }

  // deferred l reduction (keys split across quads -> xor 16, 32)
  float inv[2];
#pragma unroll
  for (int nt = 0; nt < 2; nt++) {
    float l = l_s[nt];
    l += __shfl_xor(l, 16);
    l += __shfl_xor(l, 32);
    inv[nt] = 1.0f / l;
  }

  // epilogue: O^T C-layout row=d=mt*16+quad*4+r, col=q=ln -> Out[b][s][h*128+d]
  int b = bh >> 4, h = bh & 15;
#pragma unroll
  for (int nt = 0; nt < 2; nt++) {
    int srow = q0 + wave * 32 + nt * 16 + ln;
    size_t base = ((size_t)b * SEQ + srow) * DIM + h * HD;
#pragma unroll
    for (int mt = 0; mt < 8; mt++) {
      int d = mt * 16 + quad * 4;
      u16x4 o = { f2bf(oacc[mt][nt][0] * inv[nt]), f2bf(oacc[mt][nt][1] * inv[nt]),
                  f2bf(oacc[mt][nt][2] * inv[nt]), f2bf(oacc[mt][nt][3] * inv[nt]) };
      *(u16x4*)(Out + base + d) = o;
    }
  }
}

// ---------- launcher ----------
extern "C" void kernel_launch(void* const* d_in, const int* in_sizes, int n_in,
                              void* d_out, int out_size, void* d_ws, size_t ws_size,
                              hipStream_t stream) {
  const float* x     = (const float*)d_in[0];
  const float* w_qkv = (const float*)d_in[1];
  const float* b_qkv = (const float*)d_in[2];
  const float* w_o   = (const float*)d_in[3];
  const float* b_o   = (const float*)d_in[4];
  float* out = (float*)d_out;

  char* ws = (char*)d_ws;
  const size_t SZ_XBF  = (size_t)MROWS * DIM * 2;     // 33.5 MB (also attn_out)
  const size_t SZ_WQKV = (size_t)3 * DIM * DIM * 2;   // 25.2 MB
  const size_t SZ_WO   = (size_t)DIM * DIM * 2;       // 8.4 MB
  const size_t SZ_HEAD = (size_t)BH * SEQ * HD * 2;   // 33.5 MB each
  u16* x_bf    = (u16*)(ws);
  u16* wqkv_bf = (u16*)(ws + SZ_XBF);
  u16* wo_bf   = (u16*)(ws + SZ_XBF + SZ_WQKV);
  u16* qbuf    = (u16*)(ws + SZ_XBF + SZ_WQKV + SZ_WO);
  u16* kbuf    = (u16*)(ws + SZ_XBF + SZ_WQKV + SZ_WO + SZ_HEAD);
  u16* vtbuf   = (u16*)(ws + SZ_XBF + SZ_WQKV + SZ_WO + 2 * SZ_HEAD);
  float* bq_s  = (float*)(ws + SZ_XBF + SZ_WQKV + SZ_WO + 3 * SZ_HEAD);
  u16* attn_out = x_bf;  // reuse: x_bf dead after GEMM1

  (void)in_sizes; (void)n_in; (void)out_size; (void)ws_size;

  // scale2 = 1/sqrt(HD) * log2(e): folded into W_q / b_q so QK^T MFMA emits
  // log2-domain scores directly.
  const float scale2 = (float)(0.08838834764831845 * 1.4426950408889634);

  // fused prologue: all converts + bias scale in ONE dispatch
  fused_cvt_kernel<<<NB_X + NB_WQ + NB_WO + NB_BIAS, 256, 0, stream>>>(
      (const float4*)x, (u16x4*)x_bf,
      (const float4*)w_qkv, (u16x4*)wqkv_bf,
      (const float4*)w_o, (u16x4*)wo_bf,
      b_qkv, bq_s, scale2);

  // GEMM1: [8192,2048] x [6144,2048]^T -> scatter q/k/vT (bf16), 256^2 tiles
  gemm_bt_kernel<1><<<(3 * DIM / 256) * (MROWS / 256), 512, 0, stream>>>(
      x_bf, wqkv_bf, bq_s, nullptr, MROWS, 3 * DIM, DIM, qbuf, kbuf, vtbuf);

  // attention: 1D grid 1024, XCD-swizzled in-kernel (bh grouped per XCD)
  attn_kernel<<<(SEQ / 128) * BH, 256, 0, stream>>>(
      qbuf, kbuf, vtbuf, attn_out);

  // GEMM2: [8192,2048] x [2048,2048]^T + b_o -> fp32 d_out, 256^2 tiles
  gemm_bt_kernel<0><<<(DIM / 256) * (MROWS / 256), 512, 0, stream>>>(
      attn_out, wo_bf, b_o, out, MROWS, DIM, DIM, nullptr, nullptr, nullptr);
}

// Round 9
// 508.985 us; speedup vs baseline: 1.0360x; 1.0360x over previous
//
#include <hip/hip_runtime.h>
#include <cstdint>
#include <cstddef>

// ---------- types ----------
typedef __attribute__((ext_vector_type(8))) __bf16 bf16x8;   // MFMA A/B frag (4 VGPRs)
typedef __attribute__((ext_vector_type(4))) float f32x4;     // MFMA C/D frag
typedef __attribute__((ext_vector_type(4))) unsigned short u16x4;
typedef unsigned short u16;

// Problem constants
#define BATCH 4
#define SEQ 2048
#define DIM 2048
#define NH 16
#define HD 128
#define BH (BATCH*NH)          // 64
#define MROWS (BATCH*SEQ)      // 8192

__device__ static inline u16 f2bf(float f) {
  union { float f; uint32_t u; } v; v.f = f;
  uint32_t r = v.u + 0x7fffu + ((v.u >> 16) & 1u);
  return (u16)(r >> 16);
}

// pack two fp32 -> two bf16 (round-half-up) in one v_perm
__device__ static inline uint32_t pkbf(float lo, float hi) {
  union { float f; uint32_t u; } a, b;
  a.f = lo; b.f = hi;
  return __builtin_amdgcn_perm(b.u + 0x8000u, a.u + 0x8000u, 0x07060302u);
}

// pack two fp32 -> two bf16 (RNE) in ONE VALU op
__device__ static inline uint32_t cvtpk(float lo, float hi) {
  uint32_t r;
  asm("v_cvt_pk_bf16_f32 %0, %1, %2" : "=v"(r) : "v"(lo), "v"(hi));
  return r;
}

__device__ static inline void gload_lds16(const void* g, void* l) {
  __builtin_amdgcn_global_load_lds(
      (const __attribute__((address_space(1))) unsigned int*)g,
      (__attribute__((address_space(3))) unsigned int*)l, 16, 0, 0);
}

__device__ static inline f32x4 mfma_bf16(bf16x8 a, bf16x8 b, f32x4 c) {
  return __builtin_amdgcn_mfma_f32_16x16x32_bf16(a, b, c, 0, 0, 0);
}

// ---------- fused prologue: all fp32->bf16 converts + bias scale, ONE dispatch ----------
#define NB_X   (MROWS * DIM / 1024)       // 16384 blocks
#define NB_WQ  (3 * DIM * DIM / 1024)     // 12288 blocks
#define NB_WO  (DIM * DIM / 1024)         // 4096 blocks
#define NB_BIAS (3 * DIM / 256)           // 24 blocks
__global__ __launch_bounds__(256) void fused_cvt_kernel(
    const float4* __restrict__ x, u16x4* __restrict__ xb,
    const float4* __restrict__ wq, u16x4* __restrict__ wqb,
    const float4* __restrict__ wo, u16x4* __restrict__ wob,
    const float* __restrict__ bq, float* __restrict__ bqs, float scale2) {
  const int b = blockIdx.x;
  const int t = threadIdx.x;
  if (b < NB_X) {
    int i = b * 256 + t;
    float4 f = x[i];
    u16x4 o = { f2bf(f.x), f2bf(f.y), f2bf(f.z), f2bf(f.w) };
    xb[i] = o;
  } else if (b < NB_X + NB_WQ) {
    int i = (b - NB_X) * 256 + t;
    float4 f = wq[i];
    float s = (i < DIM * DIM / 4) ? scale2 : 1.0f;
    u16x4 o = { f2bf(f.x * s), f2bf(f.y * s), f2bf(f.z * s), f2bf(f.w * s) };
    wqb[i] = o;
  } else if (b < NB_X + NB_WQ + NB_WO) {
    int i = (b - NB_X - NB_WQ) * 256 + t;
    float4 f = wo[i];
    u16x4 o = { f2bf(f.x), f2bf(f.y), f2bf(f.z), f2bf(f.w) };
    wob[i] = o;
  } else {
    int i = (b - NB_X - NB_WQ - NB_WO) * 256 + t;
    bqs[i] = bq[i] * ((i < DIM) ? scale2 : 1.0f);
  }
}

// ---------- GEMM fragment helpers (256x256, 4 merged phases) ----------
__device__ __forceinline__ void ld_a(const char* sA, int wm, int ln, int quad,
                                     bf16x8 (&af)[4][2]) {
#pragma unroll
  for (int i = 0; i < 4; i++) {
    int r = wm * 64 + i * 16 + ln;
#pragma unroll
    for (int ks = 0; ks < 2; ks++) {
      int c = (ks * 4 + quad) ^ (r & 7);
      af[i][ks] = *(const bf16x8*)(sA + r * 128 + c * 16);
    }
  }
}

__device__ __forceinline__ void ld_b(const char* sB, int wn, int ln, int quad,
                                     bf16x8 (&bf)[2][2]) {
#pragma unroll
  for (int j = 0; j < 2; j++) {
    int r = wn * 32 + j * 16 + ln;
#pragma unroll
    for (int ks = 0; ks < 2; ks++) {
      int c = (ks * 4 + quad) ^ (r & 7);
      bf[j][ks] = *(const bf16x8*)(sB + r * 128 + c * 16);
    }
  }
}

template<int QM, int QN>
__device__ __forceinline__ void mm16(f32x4 (&acc)[8][4], const bf16x8 (&af)[4][2],
                                     const bf16x8 (&bf)[2][2]) {
  __builtin_amdgcn_s_setprio(1);
#pragma unroll
  for (int i = 0; i < 4; i++)
#pragma unroll
    for (int j = 0; j < 2; j++)
#pragma unroll
      for (int ks = 0; ks < 2; ks++)
        acc[QM * 4 + i][QN * 2 + j] =
            mfma_bf16(af[i][ks], bf[j][ks], acc[QM * 4 + i][QN * 2 + j]);
  __builtin_amdgcn_s_setprio(0);
}

// ---------- GEMM: C[M,N] = A[M,K] * W[N,K]^T + bias ----------
// 256x256 tile, BK=64, 8 waves (2M x 4N). R9: 4 MERGED phases/iter (2 k-tiles),
// 32 MFMA per barrier (was 16), counted vmcnt(4) at mp2/mp4.
// Stage placement (slot -> staged in phase AFTER its last reader, drained by
// the BARV before its next reader — verified by induction, steady-state
// outstanding 4->8->12->drain-to-4):
//   mp1: reads A00,B00,B01(t); stages B11,A11 @t+1; MFMA q00,q01(t)
//   mp2: reads A01(t);         stages A00,B00 @t+2; MFMA q10,q11(t); BARV(4)
//   mp3: reads A10,B10,B11(t+1); stages B01,A01 @t+2; MFMA q00,q01(t+1)
//   mp4: reads A11(t+1);       stages A10,B10 @t+3; MFMA q10,q11(t+1); BARV(4)
// XCD swizzle, bx-OUTER / by-INNER (gy == 32 both launches).
template<int EPI>
__global__ __launch_bounds__(512, 2) void gemm_bt_kernel(
    const u16* __restrict__ A, const u16* __restrict__ W,
    const float* __restrict__ bias, float* __restrict__ Cout,
    int M, int N, int K,
    u16* __restrict__ qb, u16* __restrict__ kb, u16* __restrict__ vtb) {
  __shared__ __align__(16) char lds[131072];

  const int tid = threadIdx.x;
  const int wave = tid >> 6, lane = tid & 63;
  const int quad = lane >> 4, ln = lane & 15;
  const int wm = wave >> 2;             // 0..1
  const int wn = wave & 3;              // 0..3

  // XCD-aware swizzle (nwg % 8 == 0; gy = M/256 = 32 -> 4 rows/XCD)
  const int bid = blockIdx.x;
  const int c = bid & 7;                // XCD id
  const int u = bid >> 3;               // within-XCD index
  const int bx = u >> 2;                // bx-outer
  const int by = c * 4 + (u & 3);       // by-inner, contiguous per XCD
  const int mbase = by * 256;
  const int nbase = bx * 256;

  f32x4 acc[8][4];
#pragma unroll
  for (int i = 0; i < 8; i++)
#pragma unroll
    for (int j = 0; j < 4; j++) acc[i][j] = (f32x4){0.f, 0.f, 0.f, 0.f};

  // loop-invariant staging geometry: one granule = 1024 chunks x 16B = 16KB,
  // chunk = wave*128 + issue*64 + lane (linear LDS dest for global_load_lds).
  const u16* gA[2][2];  // [granule][issue]
  const u16* gB[2][2];
  int stOff0, stOff1;
  {
    stOff0 = (wave * 128 + lane) * 16;
    stOff1 = stOff0 + 1024;
#pragma unroll
    for (int s = 0; s < 2; s++) {
      int chunk = wave * 128 + s * 64 + lane;
      int r = chunk >> 3, sc = chunk & 7;
      int gc = sc ^ (r & 7);             // pre-swizzled global 16B chunk
#pragma unroll
      for (int g = 0; g < 2; g++) {
        int ra = (r >> 6) * 128 + g * 64 + (r & 63);
        gA[g][s] = A + (size_t)(mbase + ra) * K + gc * 8;
        int rb = (r >> 5) * 64 + g * 32 + (r & 31);
        gB[g][s] = W + (size_t)(nbase + rb) * K + gc * 8;
      }
    }
  }

  const int NT = K >> 6;                 // 32 k-tiles (power of 2)
  const int NITER = NT >> 1;             // 16 iterations x 2 k-tiles

#define SLOT_A(d, g) (lds + (((d) * 2 + (g)) << 14))
#define SLOT_B(d, g) (lds + 65536 + (((d) * 2 + (g)) << 14))
#define STAGE_A(d, t, g) do { char* sb_ = SLOT_A(d, g); \
    size_t ko_ = (size_t)((t) & (NT - 1)) * 64; \
    gload_lds16(gA[g][0] + ko_, sb_ + stOff0); \
    gload_lds16(gA[g][1] + ko_, sb_ + stOff1); } while (0)
#define STAGE_B(d, t, g) do { char* sb_ = SLOT_B(d, g); \
    size_t ko_ = (size_t)((t) & (NT - 1)) * 64; \
    gload_lds16(gB[g][0] + ko_, sb_ + stOff0); \
    gload_lds16(gB[g][1] + ko_, sb_ + stOff1); } while (0)
#define BAR  asm volatile("s_barrier" ::: "memory")
#define BARV asm volatile("s_waitcnt vmcnt(4)\n\ts_barrier" ::: "memory")

  // prologue: k-tile 0 fully (8 loads) + k-tile 1 granule-0 A/B (4 loads);
  // vmcnt(4) drains the oldest 8 = all of k-tile 0.
  STAGE_A(0, 0, 0); STAGE_B(0, 0, 0); STAGE_A(0, 0, 1); STAGE_B(0, 0, 1);
  STAGE_A(1, 1, 0); STAGE_B(1, 1, 0);
  BARV;

  for (int it = 0; it < NITER; ++it) {
    const int t = it << 1;               // even: k-tile t in d=0, t+1 in d=1
    bf16x8 af[4][2], bq0[2][2], bq1[2][2];
    // ---- mp1: quadrants (0,0),(0,1) of tile t ----
    ld_a(SLOT_A(0, 0), wm, ln, quad, af);
    ld_b(SLOT_B(0, 0), wn, ln, quad, bq0);
    ld_b(SLOT_B(0, 1), wn, ln, quad, bq1);
    STAGE_B(1, t + 1, 1);                // B-g1(t-1) last read prev mp3
    STAGE_A(1, t + 1, 1);                // A-g1(t-1) last read prev mp4
    mm16<0, 0>(acc, af, bq0);
    mm16<0, 1>(acc, af, bq1);
    BAR;
    // ---- mp2: quadrants (1,0),(1,1) of tile t ----
    ld_a(SLOT_A(0, 1), wm, ln, quad, af);
    STAGE_A(0, t + 2, 0);                // A-g0(t) read in mp1
    STAGE_B(0, t + 2, 0);                // B-g0(t) read in mp1
    mm16<1, 0>(acc, af, bq0);
    mm16<1, 1>(acc, af, bq1);
    BARV;                                 // drains prev-mp4 + mp1 stages
    // ---- mp3: quadrants (0,0),(0,1) of tile t+1 ----
    ld_a(SLOT_A(1, 0), wm, ln, quad, af);
    ld_b(SLOT_B(1, 0), wn, ln, quad, bq0);
    ld_b(SLOT_B(1, 1), wn, ln, quad, bq1);
    STAGE_B(0, t + 2, 1);                // B-g1(t) read in mp1
    STAGE_A(0, t + 2, 1);                // A-g1(t) read in mp2
    mm16<0, 0>(acc, af, bq0);
    mm16<0, 1>(acc, af, bq1);
    BAR;
    // ---- mp4: quadrants (1,0),(1,1) of tile t+1 ----
    ld_a(SLOT_A(1, 1), wm, ln, quad, af);
    STAGE_A(1, t + 3, 0);                // A-g0(t+1) read in mp3
    STAGE_B(1, t + 3, 0);                // B-g0(t+1) read in mp3
    mm16<1, 0>(acc, af, bq0);
    mm16<1, 1>(acc, af, bq1);
    BARV;                                 // drains mp2 + mp3 stages
  }
#undef SLOT_A
#undef SLOT_B
#undef STAGE_A
#undef STAGE_B
#undef BAR
#undef BARV

  // epilogue. C/D layout: col = lane&15, row = quad*4 + reg.
  // row = mbase + wm*128 + i*16 + quad*4 + r ; col = nbase + wn*64 + j*16 + ln
  if (EPI == 0 || (nbase >> 11) < 2) {
#pragma unroll
    for (int i = 0; i < 8; i++) {
#pragma unroll
      for (int j = 0; j < 4; j++) {
        int col = nbase + wn * 64 + j * 16 + ln;
        float bv = bias[col];
#pragma unroll
        for (int r = 0; r < 4; r++) {
          int row = mbase + wm * 128 + i * 16 + quad * 4 + r;
          float val = acc[i][j][r] + bv;
          if (EPI == 0) {
            Cout[(size_t)row * N + col] = val;
          } else {
            int b = row >> 11, s = row & 2047;
            int m3 = col >> 11, h = (col >> 7) & 15, d = col & 127;
            int bh = b * NH + h;
            u16 bfv = f2bf(val);
            if (m3 == 0) qb[((size_t)bh * SEQ + s) * HD + d] = bfv;
            else         kb[((size_t)bh * SEQ + s) * HD + d] = bfv;
          }
        }
      }
    }
  } else {
    // V block: transpose via LDS. Full tile = 256 cols(d) x 256 rows(s) bf16
    // = 128KB (exactly fits). Row = 512B = 32 x 16B chunks, chunk index
    // XOR-swizzled with (col&31). Wrap-staged gloads still target LDS:
    // drain ALL waves' vmem-LDS writes before reuse (vmcnt per-wave -> +barrier).
    asm volatile("s_waitcnt vmcnt(0)" ::: "memory");
    __syncthreads();
#pragma unroll
    for (int i = 0; i < 8; i++) {
      int rl0 = wm * 128 + i * 16 + quad * 4;   // 4 consecutive s-rows
      int cs = rl0 >> 3;                         // 16B chunk in s-dim (0..31)
      int half = (quad & 1);                     // 8B half of the chunk
#pragma unroll
      for (int j = 0; j < 4; j++) {
        int cl = wn * 64 + j * 16 + ln;          // col_local = d-dim 0..255
        float bv = bias[nbase + cl];
        uint2 w2;
        w2.x = pkbf(acc[i][j][0] + bv, acc[i][j][1] + bv);
        w2.y = pkbf(acc[i][j][2] + bv, acc[i][j][3] + bv);
        int cc = cs ^ (cl & 31);
        *(uint2*)(lds + cl * 512 + cc * 16 + half * 8) = w2;
      }
    }
    __syncthreads();
    // vtb[bh][d][s]: heads contiguous -> linear in cl since nbase%256==0
    u16* vdst = vtb + ((size_t)((mbase >> 11) * 2048 + (nbase & 2047))) * SEQ
                + (mbase & 2047);
#pragma unroll
    for (int rd = 0; rd < 16; rd++) {
      int idx = rd * 512 + tid;                  // 0..8191
      int cl = idx >> 5, cs = idx & 31;
      f32x4 v = *(const f32x4*)(lds + cl * 512 + ((cs ^ (cl & 31)) * 16));
      *(f32x4*)(vdst + (size_t)cl * SEQ + cs * 8) = v;
    }
  }
}

// ---------- flash attention (S^T, fixed-M softmax, double-buffered staging) ----------
// R7 version exactly (511us total run): KVB=64, 80KB LDS, 2 blocks/CU,
// XCD swizzle, setprio, cvt_pk P-pack, raw v_exp_f32, no softmax shift
// (2^s cancels exactly in O/l; scores bounded).
// R8's SM/PV pipeline REVERTED: single-wave in-order issue means source-level
// reordering gives no MFMA/VALU overlap (T15/m253 non-transfer re-confirmed:
// +16us regression, GEMMs byte-identical).
__global__ __launch_bounds__(256, 2) void attn_kernel(
    const u16* __restrict__ Q, const u16* __restrict__ Km,
    const u16* __restrict__ Vt, u16* __restrict__ Out) {
  __shared__ __align__(16) char lds[81920];
  // buf0: K[0..16K) V[16K..32K); buf1: K[32K..48K) V[48K..64K); P at 64K.
  char* ldsP = lds + 65536;          // per wave 4KB: [32 q][128B] swizzled (&7)

  const int tid = threadIdx.x;
  const int wave = tid >> 6, lane = tid & 63;
  const int quad = lane >> 4, ln = lane & 15;

  // XCD swizzle: XCD c (wg%8==c) gets bh in [8c, 8c+8), q-tile fastest.
  const int wg = blockIdx.x;
  const int swz = (wg & 7) * 128 + (wg >> 3);
  const int bh = swz >> 4;
  const int q0 = (swz & 15) * 128;

  const u16* Qb = Q + (size_t)bh * SEQ * HD;
  const u16* Kb = Km + (size_t)bh * SEQ * HD;
  const u16* Vb = Vt + (size_t)bh * HD * SEQ;

  // Q fragments (bytes serve as MFMA B-operand: B[k=quad*8+j][n=ln])
  bf16x8 qf[2][4];
#pragma unroll
  for (int nt = 0; nt < 2; nt++)
#pragma unroll
    for (int ks = 0; ks < 4; ks++) {
      int row = q0 + wave * 32 + nt * 16 + ln;
      qf[nt][ks] = *(const bf16x8*)(Qb + (size_t)row * HD + ks * 32 + quad * 8);
    }

  // O^T accumulators: [8 d-tiles][2 q-tiles], C-layout row=d, col=q=ln
  f32x4 oacc[8][2];
#pragma unroll
  for (int mt = 0; mt < 8; mt++)
#pragma unroll
    for (int nt = 0; nt < 2; nt++) oacc[mt][nt] = (f32x4){0.f, 0.f, 0.f, 0.f};
  float l_s[2] = {0.f, 0.f};

  char* Pw = ldsP + wave * 4096;

  // per-lane staging geometry (loop-invariant)
  const int chunk0 = wave * 256 + lane;
  const u16* gKp[4]; const u16* gVp[4]; int ldsOff[4];
#pragma unroll
  for (int s4 = 0; s4 < 4; s4++) {
    int chunk = chunk0 + s4 * 64;              // 0..1023
    int rk = chunk >> 4, ck = chunk & 15;
    int gk = ck ^ (rk & 15);
    gKp[s4] = Kb + (size_t)rk * HD + gk * 8;
    int rv = chunk >> 3, cv = chunk & 7;
    int gv = cv ^ (rv & 7);
    gVp[s4] = Vb + (size_t)rv * SEQ + gv * 8;
    ldsOff[s4] = chunk * 16;
  }

  // prologue: stage tile 0 into buf0
#pragma unroll
  for (int s4 = 0; s4 < 4; s4++) {
    gload_lds16(gKp[s4], lds + ldsOff[s4]);
    gload_lds16(gVp[s4], lds + 16384 + ldsOff[s4]);
  }

  for (int kt = 0; kt < SEQ / 64; kt++) {
    // stage tile kt+1 (wraps to 0 on last iter — idle buffer, harmless)
    {
      int t = (kt + 1) & (SEQ / 64 - 1);
      char* buf = lds + ((kt + 1) & 1) * 32768;
#pragma unroll
      for (int s4 = 0; s4 < 4; s4++) {
        gload_lds16(gKp[s4] + (size_t)t * 64 * HD, buf + ldsOff[s4]);
        gload_lds16(gVp[s4] + t * 64, buf + 16384 + ldsOff[s4]);
      }
    }
    // wait for tile kt's 8 loads (the 8 just issued stay in flight) + sync
    asm volatile("s_waitcnt vmcnt(8)\n\ts_barrier" ::: "memory");

    const char* ldsK = lds + (kt & 1) * 32768;
    const char* ldsV = ldsK + 16384;

    // S^T = K·Q^T : [4 key-tiles][2 q-tiles] (log2-domain scores)
    f32x4 st[4][2];
#pragma unroll
    for (int mt = 0; mt < 4; mt++)
#pragma unroll
      for (int nt = 0; nt < 2; nt++) st[mt][nt] = (f32x4){0.f, 0.f, 0.f, 0.f};
    __builtin_amdgcn_s_setprio(1);
#pragma unroll
    for (int ks = 0; ks < 4; ks++) {
      bf16x8 kf[4];
#pragma unroll
      for (int mt = 0; mt < 4; mt++) {
        int row = mt * 16 + ln;
        int ch = (ks * 4 + quad) ^ (row & 15);
        kf[mt] = *(const bf16x8*)(ldsK + row * 256 + ch * 16);
      }
#pragma unroll
      for (int mt = 0; mt < 4; mt++)
#pragma unroll
        for (int nt = 0; nt < 2; nt++)
          st[mt][nt] = mfma_bf16(kf[mt], qf[nt][ks], st[mt][nt]);
    }
    __builtin_amdgcn_s_setprio(0);

    // fixed-M softmax: p = exp2(s), in-lane l partial, swizzled b64 P store
#pragma unroll
    for (int nt = 0; nt < 2; nt++) {
      float lp = 0.f;
      u16* prow = (u16*)(Pw + (nt * 16 + ln) * 128);
#pragma unroll
      for (int mt = 0; mt < 4; mt++) {
        float p0 = __builtin_amdgcn_exp2f(st[mt][nt][0]);
        float p1 = __builtin_amdgcn_exp2f(st[mt][nt][1]);
        float p2 = __builtin_amdgcn_exp2f(st[mt][nt][2]);
        float p3 = __builtin_amdgcn_exp2f(st[mt][nt][3]);
        lp += (p0 + p1) + (p2 + p3);
        uint2 w2;
        w2.x = cvtpk(p0, p1);
        w2.y = cvtpk(p2, p3);
        int cc = (mt * 2 + (quad >> 1)) ^ (ln & 7);
        *(uint2*)((char*)prow + cc * 16 + (quad & 1) * 8) = w2;
      }
      l_s[nt] += lp;
    }
    asm volatile("s_waitcnt lgkmcnt(0)" ::: "memory");  // P writes visible (own wave)

    // O^T += V^T·P^T
    __builtin_amdgcn_s_setprio(1);
#pragma unroll
    for (int ks2 = 0; ks2 < 2; ks2++) {
      bf16x8 pb[2];
#pragma unroll
      for (int nt = 0; nt < 2; nt++) {
        int cc = (ks2 * 4 + quad) ^ (ln & 7);
        pb[nt] = *(const bf16x8*)(Pw + (nt * 16 + ln) * 128 + cc * 16);
      }
      bf16x8 vf[8];
#pragma unroll
      for (int mt = 0; mt < 8; mt++) {
        int row = mt * 16 + ln;
        int ch = (ks2 * 4 + quad) ^ (row & 7);
        vf[mt] = *(const bf16x8*)(ldsV + row * 128 + ch * 16);
      }
#pragma unroll
      for (int mt = 0; mt < 8; mt++)
#pragma unroll
        for (int nt = 0; nt < 2; nt++)
          oacc[mt][nt] = mfma_bf16(vf[mt], pb[nt], oacc[mt][nt]);
    }
    __builtin_amdgcn_s_setprio(0);
    // all waves done reading buf[kt&1] before next iter's staging overwrites it
    asm volatile("s_waitcnt lgkmcnt(0)\n\ts_barrier" ::: "memory");
  }

  // deferred l reduction (keys split across quads -> xor 16, 32)
  float inv[2];
#pragma unroll
  for (int nt = 0; nt < 2; nt++) {
    float l = l_s[nt];
    l += __shfl_xor(l, 16);
    l += __shfl_xor(l, 32);
    inv[nt] = 1.0f / l;
  }

  // epilogue: O^T C-layout row=d=mt*16+quad*4+r, col=q=ln -> Out[b][s][h*128+d]
  int b = bh >> 4, h = bh & 15;
#pragma unroll
  for (int nt = 0; nt < 2; nt++) {
    int srow = q0 + wave * 32 + nt * 16 + ln;
    size_t base = ((size_t)b * SEQ + srow) * DIM + h * HD;
#pragma unroll
    for (int mt = 0; mt < 8; mt++) {
      int d = mt * 16 + quad * 4;
      u16x4 o = { f2bf(oacc[mt][nt][0] * inv[nt]), f2bf(oacc[mt][nt][1] * inv[nt]),
                  f2bf(oacc[mt][nt][2] * inv[nt]), f2bf(oacc[mt][nt][3] * inv[nt]) };
      *(u16x4*)(Out + base + d) = o;
    }
  }
}

// ---------- launcher ----------
extern "C" void kernel_launch(void* const* d_in, const int* in_sizes, int n_in,
                              void* d_out, int out_size, void* d_ws, size_t ws_size,
                              hipStream_t stream) {
  const float* x     = (const float*)d_in[0];
  const float* w_qkv = (const float*)d_in[1];
  const float* b_qkv = (const float*)d_in[2];
  const float* w_o   = (const float*)d_in[3];
  const float* b_o   = (const float*)d_in[4];
  float* out = (float*)d_out;

  char* ws = (char*)d_ws;
  const size_t SZ_XBF  = (size_t)MROWS * DIM * 2;     // 33.5 MB (also attn_out)
  const size_t SZ_WQKV = (size_t)3 * DIM * DIM * 2;   // 25.2 MB
  const size_t SZ_WO   = (size_t)DIM * DIM * 2;       // 8.4 MB
  const size_t SZ_HEAD = (size_t)BH * SEQ * HD * 2;   // 33.5 MB each
  u16* x_bf    = (u16*)(ws);
  u16* wqkv_bf = (u16*)(ws + SZ_XBF);
  u16* wo_bf   = (u16*)(ws + SZ_XBF + SZ_WQKV);
  u16* qbuf    = (u16*)(ws + SZ_XBF + SZ_WQKV + SZ_WO);
  u16* kbuf    = (u16*)(ws + SZ_XBF + SZ_WQKV + SZ_WO + SZ_HEAD);
  u16* vtbuf   = (u16*)(ws + SZ_XBF + SZ_WQKV + SZ_WO + 2 * SZ_HEAD);
  float* bq_s  = (float*)(ws + SZ_XBF + SZ_WQKV + SZ_WO + 3 * SZ_HEAD);
  u16* attn_out = x_bf;  // reuse: x_bf dead after GEMM1

  (void)in_sizes; (void)n_in; (void)out_size; (void)ws_size;

  // scale2 = 1/sqrt(HD) * log2(e): folded into W_q / b_q so QK^T MFMA emits
  // log2-domain scores directly.
  const float scale2 = (float)(0.08838834764831845 * 1.4426950408889634);

  // fused prologue: all converts + bias scale in ONE dispatch
  fused_cvt_kernel<<<NB_X + NB_WQ + NB_WO + NB_BIAS, 256, 0, stream>>>(
      (const float4*)x, (u16x4*)x_bf,
      (const float4*)w_qkv, (u16x4*)wqkv_bf,
      (const float4*)w_o, (u16x4*)wo_bf,
      b_qkv, bq_s, scale2);

  // GEMM1: [8192,2048] x [6144,2048]^T -> scatter q/k/vT (bf16), 256^2 tiles
  gemm_bt_kernel<1><<<(3 * DIM / 256) * (MROWS / 256), 512, 0, stream>>>(
      x_bf, wqkv_bf, bq_s, nullptr, MROWS, 3 * DIM, DIM, qbuf, kbuf, vtbuf);

  // attention: 1D grid 1024, XCD-swizzled in-kernel (bh grouped per XCD)
  attn_kernel<<<(SEQ / 128) * BH, 256, 0, stream>>>(
      qbuf, kbuf, vtbuf, attn_out);

  // GEMM2: [8192,2048] x [2048,2048]^T + b_o -> fp32 d_out, 256^2 tiles
  gemm_bt_kernel<0><<<(DIM / 256) * (MROWS / 256), 512, 0, stream>>>(
      attn_out, wo_bf, b_o, out, MROWS, DIM, DIM, nullptr, nullptr, nullptr);
}